// Round 1
// baseline (12223.808 us; speedup 1.0000x reference)
//
#include <hip/hip_runtime.h>

#define DIV_UP(a,b) (((a)+(b)-1)/(b))

// ---------------------------------------------------------------------------
// Direct 3x3 SAME conv + bias + ReLU. One thread per output pixel.
// grid: (ceil(H*W/256), Cout, N)   block: 256
// Weights indexed uniformly per block (co from blockIdx.y) -> scalar loads.
// ---------------------------------------------------------------------------
__global__ __launch_bounds__(256)
void conv3x3_relu(const float* __restrict__ in, const float* __restrict__ wgt,
                  const float* __restrict__ bias, float* __restrict__ out,
                  int Cin, int Cout, int H, int W) {
    int HW = H * W;
    int hw = blockIdx.x * blockDim.x + threadIdx.x;
    if (hw >= HW) return;
    int co = blockIdx.y;
    int n  = blockIdx.z;
    int h = hw / W, w = hw % W;

    float acc = bias[co];
    const float* wp = wgt + (size_t)co * Cin * 9;
    const float* ip = in + (size_t)(n * Cin) * HW;

    for (int ci = 0; ci < Cin; ++ci) {
        const float* iprow = ip + (size_t)ci * HW;
        const float* wrow  = wp + ci * 9;
#pragma unroll
        for (int kh = 0; kh < 3; ++kh) {
            int ih = h + kh - 1;
            if (ih < 0 || ih >= H) continue;
            const float* r = iprow + (size_t)ih * W;
#pragma unroll
            for (int kw = 0; kw < 3; ++kw) {
                int iw = w + kw - 1;
                if (iw < 0 || iw >= W) continue;
                acc = fmaf(r[iw], wrow[kh * 3 + kw], acc);
            }
        }
    }
    out[(size_t)(n * Cout + co) * HW + hw] = fmaxf(acc, 0.f);
}

// ---------------------------------------------------------------------------
// 2x2 max pool, stride 2. One thread per output element.
// ---------------------------------------------------------------------------
__global__ __launch_bounds__(256)
void maxpool2(const float* __restrict__ in, float* __restrict__ out,
              int C, int H, int W) {
    int Ho = H >> 1, Wo = W >> 1;
    int total = 2 * C * Ho * Wo;
    int idx = blockIdx.x * blockDim.x + threadIdx.x;
    if (idx >= total) return;
    int wo = idx % Wo;
    int t  = idx / Wo;
    int ho = t % Ho;
    t /= Ho;                       // t = n*C + c
    const float* p = in + ((size_t)t * H + ho * 2) * W + wo * 2;
    float m = fmaxf(fmaxf(p[0], p[1]), fmaxf(p[W], p[W + 1]));
    out[idx] = m;
}

// ---------------------------------------------------------------------------
// Per-channel min/max over (batch, spatial). One block per channel.
// ---------------------------------------------------------------------------
__global__ __launch_bounds__(256)
void chan_minmax(const float* __restrict__ in, float* __restrict__ mn,
                 float* __restrict__ mx, int C, int HW) {
    int c = blockIdx.x;
    float lmn = INFINITY, lmx = -INFINITY;
    for (int n = 0; n < 2; ++n) {
        const float* p = in + (size_t)(n * C + c) * HW;
        for (int i = threadIdx.x; i < HW; i += blockDim.x) {
            float v = p[i];
            lmn = fminf(lmn, v);
            lmx = fmaxf(lmx, v);
        }
    }
    __shared__ float smn[4], smx[4];
#pragma unroll
    for (int off = 32; off >= 1; off >>= 1) {
        lmn = fminf(lmn, __shfl_down(lmn, off, 64));
        lmx = fmaxf(lmx, __shfl_down(lmx, off, 64));
    }
    int wave = threadIdx.x >> 6;
    if ((threadIdx.x & 63) == 0) { smn[wave] = lmn; smx[wave] = lmx; }
    __syncthreads();
    if (threadIdx.x == 0) {
        float a = smn[0], b = smx[0];
        for (int i = 1; i < 4; ++i) { a = fminf(a, smn[i]); b = fmaxf(b, smx[i]); }
        mn[c] = a; mx[c] = b;
    }
}

// ---------------------------------------------------------------------------
// Fake-quant apply (forward value): x = mn + rint((x-mn)*255/zd) * (zd/255)
// rintf == round-half-to-even == jnp.round
// ---------------------------------------------------------------------------
__global__ __launch_bounds__(256)
void quant_apply(float* __restrict__ x, const float* __restrict__ mn,
                 const float* __restrict__ mx, int C, int HW) {
    int total = 2 * C * HW;
    int idx = blockIdx.x * blockDim.x + threadIdx.x;
    if (idx >= total) return;
    int c = (idx / HW) % C;
    float m = mn[c];
    float zd = mx[c] - m;
    float s = 255.f / zd;
    float inv = zd / 255.f;
    float v = x[idx];
    x[idx] = m + rintf((v - m) * s) * inv;
}

// ---------------------------------------------------------------------------
// FC helpers: init out with bias, split-K accumulate with atomics, relu.
// out layout: [2, dout] row-major.  h layout: [2, din] row-major.
// w layout: [din, dout] row-major (so lanes over dout are coalesced).
// ---------------------------------------------------------------------------
__global__ __launch_bounds__(256)
void fc_init(const float* __restrict__ b, float* __restrict__ out, int dout) {
    int i = blockIdx.x * blockDim.x + threadIdx.x;
    if (i < 2 * dout) out[i] = b[i % dout];
}

__global__ __launch_bounds__(256)
void fc_splitk(const float* __restrict__ h, const float* __restrict__ w,
               float* __restrict__ out, int din, int dout, int chunk) {
    int o4 = blockIdx.x * blockDim.x + threadIdx.x;
    int o = o4 * 4;
    if (o >= dout) return;
    int d0 = blockIdx.y * chunk;
    int d1 = min(d0 + chunk, din);
    float4 a0 = {0.f, 0.f, 0.f, 0.f};
    float4 a1 = {0.f, 0.f, 0.f, 0.f};
    for (int d = d0; d < d1; ++d) {
        float4 wv = *(const float4*)(w + (size_t)d * dout + o);
        float h0 = h[d];
        float h1 = h[din + d];
        a0.x = fmaf(h0, wv.x, a0.x); a0.y = fmaf(h0, wv.y, a0.y);
        a0.z = fmaf(h0, wv.z, a0.z); a0.w = fmaf(h0, wv.w, a0.w);
        a1.x = fmaf(h1, wv.x, a1.x); a1.y = fmaf(h1, wv.y, a1.y);
        a1.z = fmaf(h1, wv.z, a1.z); a1.w = fmaf(h1, wv.w, a1.w);
    }
    atomicAdd(&out[o + 0], a0.x); atomicAdd(&out[o + 1], a0.y);
    atomicAdd(&out[o + 2], a0.z); atomicAdd(&out[o + 3], a0.w);
    atomicAdd(&out[dout + o + 0], a1.x); atomicAdd(&out[dout + o + 1], a1.y);
    atomicAdd(&out[dout + o + 2], a1.z); atomicAdd(&out[dout + o + 3], a1.w);
}

__global__ __launch_bounds__(256)
void relu_k(float* __restrict__ x, int n) {
    int i = blockIdx.x * blockDim.x + threadIdx.x;
    if (i < n) x[i] = fmaxf(x[i], 0.f);
}

// ---------------------------------------------------------------------------
// Host-side orchestration
// ---------------------------------------------------------------------------
extern "C" void kernel_launch(void* const* d_in, const int* in_sizes, int n_in,
                              void* d_out, int out_size, void* d_ws, size_t ws_size,
                              hipStream_t stream) {
    const float* x = (const float*)d_in[0];
    const float* cw[13];
    const float* cb[13];
    for (int i = 0; i < 13; ++i) {
        cw[i] = (const float*)d_in[1 + 2 * i];
        cb[i] = (const float*)d_in[2 + 2 * i];
    }
    const float* fw1 = (const float*)d_in[27];
    const float* fb1 = (const float*)d_in[28];
    const float* fw2 = (const float*)d_in[29];
    const float* fb2 = (const float*)d_in[30];
    const float* fw3 = (const float*)d_in[31];
    const float* fb3 = (const float*)d_in[32];

    // workspace layout
    const size_t BUF = 25690112;  // 2*64*224*224*4 bytes (largest activation)
    char* ws = (char*)d_ws;
    float* bufA = (float*)ws;
    float* bufB = (float*)(ws + BUF);
    float* mn   = (float*)(ws + 2 * BUF);
    float* mx   = mn + 64;
    float* fc1  = mx + 64;        // 2*4096
    float* fc2  = fc1 + 8192;     // 2*4096

    auto conv = [&](const float* in, int layer, float* out,
                    int Cin, int Cout, int H, int W) {
        dim3 g(DIV_UP(H * W, 256), Cout, 2);
        conv3x3_relu<<<g, 256, 0, stream>>>(in, cw[layer], cb[layer], out,
                                            Cin, Cout, H, W);
    };
    auto pool = [&](const float* in, float* out, int C, int H, int W) {
        int total = 2 * C * (H / 2) * (W / 2);
        maxpool2<<<DIV_UP(total, 256), 256, 0, stream>>>(in, out, C, H, W);
    };

    // ---- features ----
    conv(x,    0, bufA, 3,   64, 224, 224);
    conv(bufA, 1, bufB, 64,  64, 224, 224);
    pool(bufB, bufA, 64, 224, 224);                       // [2,64,112,112]
    {   // fake-quant after partition conv
        int HW = 112 * 112;
        chan_minmax<<<64, 256, 0, stream>>>(bufA, mn, mx, 64, HW);
        quant_apply<<<DIV_UP(2 * 64 * HW, 256), 256, 0, stream>>>(bufA, mn, mx, 64, HW);
    }
    conv(bufA, 2, bufB, 64,  128, 112, 112);
    conv(bufB, 3, bufA, 128, 128, 112, 112);
    pool(bufA, bufB, 128, 112, 112);                      // [2,128,56,56]
    conv(bufB, 4, bufA, 128, 256, 56, 56);
    conv(bufA, 5, bufB, 256, 256, 56, 56);
    conv(bufB, 6, bufA, 256, 256, 56, 56);
    pool(bufA, bufB, 256, 56, 56);                        // [2,256,28,28]
    conv(bufB, 7, bufA, 256, 512, 28, 28);
    conv(bufA, 8, bufB, 512, 512, 28, 28);
    conv(bufB, 9, bufA, 512, 512, 28, 28);
    pool(bufA, bufB, 512, 28, 28);                        // [2,512,14,14]
    conv(bufB, 10, bufA, 512, 512, 14, 14);
    conv(bufA, 11, bufB, 512, 512, 14, 14);
    conv(bufB, 12, bufA, 512, 512, 14, 14);
    pool(bufA, bufB, 512, 14, 14);                        // [2,512,7,7] = h [2,25088]

    // ---- classifier ----
    auto fc = [&](const float* h, const float* w, const float* b, float* out,
                  int din, int dout, int S, bool relu) {
        fc_init<<<DIV_UP(2 * dout, 256), 256, 0, stream>>>(b, out, dout);
        int chunk = DIV_UP(din, S);
        dim3 g(DIV_UP(dout / 4, 256), S);
        fc_splitk<<<g, 256, 0, stream>>>(h, w, out, din, dout, chunk);
        if (relu) relu_k<<<DIV_UP(2 * dout, 256), 256, 0, stream>>>(out, 2 * dout);
    };
    fc(bufB, fw1, fb1, fc1,           25088, 4096, 64, true);
    fc(fc1,  fw2, fb2, fc2,           4096,  4096, 32, true);
    fc(fc2,  fw3, fb3, (float*)d_out, 4096,  196,  64, false);
}

// Round 2
// 3260.026 us; speedup vs baseline: 3.7496x; 3.7496x over previous
//
#include <hip/hip_runtime.h>
#include <hip/hip_bf16.h>

#define DIV_UP(a,b) (((a)+(b)-1)/(b))

typedef __attribute__((ext_vector_type(8))) short short8;
typedef __attribute__((ext_vector_type(16))) float floatx16;

__device__ __forceinline__ ushort f2bf(float f) {
    uint u = __builtin_bit_cast(uint, f);
    u += 0x7fffu + ((u >> 16) & 1u);
    return (ushort)(u >> 16);
}
__device__ __forceinline__ uint pk2(float a, float b) {
    union { __hip_bfloat162 h; uint u; } c;
    c.h = __float22bfloat162_rn(make_float2(a, b));
    return c.u;
}

// ---------------------------------------------------------------------------
// Implicit-GEMM conv3x3 SAME + bias + ReLU, bf16 MFMA 32x32x16.
// A = weights [Cout][KPAD] bf16 (tap-major k = tap*CIN+ci, rows zero-padded)
// B = im2col of padded fp32 input (halo = zeros -> branch-free SAME)
// Block: 64 co x 64 pixels (8x8 spatial tile), 4 waves of 32x32.
// ---------------------------------------------------------------------------
template<int CIN>
__global__ __launch_bounds__(256, 4)
void conv_mfma(const float* __restrict__ in, const ushort* __restrict__ wbf,
               const float* __restrict__ bias, float* __restrict__ out,
               int H, int W, int tw) {
    constexpr int KTOT = 9 * CIN;
    constexpr int KPAD = (KTOT + 31) & ~31;
    const int Wp = W + 2, Hp = H + 2;
    const int plane = Hp * Wp;
    const int Cout = gridDim.y * 64;

    __shared__ ushort At[64 * 40];   // 40-ushort (80 B) padded rows
    __shared__ ushort Bt[64 * 40];

    const int tid  = threadIdx.x;
    const int lane = tid & 63;
    const int wave = tid >> 6;
    const int wv   = __builtin_amdgcn_readfirstlane(wave);
    const int w0   = (blockIdx.x % tw) * 8;
    const int h0   = (blockIdx.x / tw) * 8;
    const int co0  = blockIdx.y * 64;
    const int img  = blockIdx.z;

    // B staging: lane <-> pixel of the 8x8 tile; wave <-> k-slice of 8
    const int prow = lane >> 3, pcol = lane & 7;
    const bool pix_ok = (h0 + prow < H) && (w0 + pcol < W);
    const int voff = prow * Wp + pcol;
    const int sb_lane = h0 * Wp + w0;
    const float* inb = in + (size_t)img * CIN * plane;

    // A staging: thread <-> (row, 16B segment)
    const int arow = tid >> 2, aseg = tid & 3;
    const ushort* awp = wbf + (size_t)(co0 + arow) * KPAD + aseg * 8;
    uint4* adst = (uint4*)&At[arow * 40 + aseg * 8];
    uint4* bdst = (uint4*)&Bt[lane * 40 + wv * 8];

    const int m0w = (wave & 1) * 32;
    const int n0w = (wave >> 1) * 32;
    const ushort* Ab = &At[(m0w + (lane & 31)) * 40 + ((lane >> 5) * 8)];
    const ushort* Bb = &Bt[(n0w + (lane & 31)) * 40 + ((lane >> 5) * 8)];

    floatx16 acc = {0,0,0,0,0,0,0,0,0,0,0,0,0,0,0,0};

    for (int k0 = 0; k0 < KPAD; k0 += 32) {
        uint4 av = *(const uint4*)(awp + k0);
        float bv[8];
#pragma unroll
        for (int i = 0; i < 8; ++i) {
            int kk  = k0 + wv * 8 + i;
            int tap = kk / CIN;
            int ci  = kk - tap * CIN;
            int kh  = tap / 3;
            int kw  = tap - kh * 3;
            float v = 0.f;
            if ((KTOT == KPAD || kk < KTOT) && pix_ok)
                v = inb[(ci * Hp + kh) * Wp + kw + sb_lane + voff];
            bv[i] = v;
        }
        uint4 bw4;
        bw4.x = pk2(bv[0], bv[1]); bw4.y = pk2(bv[2], bv[3]);
        bw4.z = pk2(bv[4], bv[5]); bw4.w = pk2(bv[6], bv[7]);
        __syncthreads();
        *adst = av;
        *bdst = bw4;
        __syncthreads();
        short8 a0 = *(const short8*)(Ab);
        short8 b0 = *(const short8*)(Bb);
        acc = __builtin_amdgcn_mfma_f32_32x32x16_bf16(a0, b0, acc, 0, 0, 0);
        short8 a1 = *(const short8*)(Ab + 16);
        short8 b1 = *(const short8*)(Bb + 16);
        acc = __builtin_amdgcn_mfma_f32_32x32x16_bf16(a1, b1, acc, 0, 0, 0);
    }

    // epilogue: C/D 32x32 mapping col(n)=lane&31, row(m)=(r&3)+8*(r>>2)+4*(lane>>5)
    const int p  = n0w + (lane & 31);
    const int eh = h0 + (p >> 3), ew = w0 + (p & 7);
    if (eh < H && ew < W) {
        float* ob = out + (size_t)img * Cout * plane + (size_t)(eh + 1) * Wp + (ew + 1);
#pragma unroll
        for (int r = 0; r < 16; ++r) {
            int m  = (r & 3) + 8 * (r >> 2) + 4 * (lane >> 5);
            int co = co0 + m0w + m;
            float v = acc[r] + bias[co];
            ob[(size_t)co * plane] = fmaxf(v, 0.f);
        }
    }
}

// ---------------------------------------------------------------------------
// Weight convert OIHW fp32 -> [co][KPAD] bf16 (tap-major), fused with
// zeroing the halo of the conv's destination buffer.
// ---------------------------------------------------------------------------
__global__ __launch_bounds__(256)
void wconv_zh(const float* __restrict__ src, ushort* __restrict__ dst,
              int CIN, int Cout, int wblocks,
              float* __restrict__ halo, int planes, int H, int W) {
    int KTOT = 9 * CIN;
    int KPAD = (KTOT + 31) & ~31;
    int b = blockIdx.x;
    if (b < wblocks) {
        int idx = b * 256 + threadIdx.x;
        if (idx < Cout * KPAD) {
            int co = idx / KPAD;
            int k  = idx - co * KPAD;
            ushort v = 0;
            if (k < KTOT) {
                int tap = k / CIN;
                int ci  = k - tap * CIN;
                v = f2bf(src[(size_t)(co * CIN + ci) * 9 + tap]);
            }
            dst[idx] = v;
        }
    } else {
        int pl = b - wblocks;
        if (pl >= planes) return;
        int Wp = W + 2, Hp = H + 2;
        float* p = halo + (size_t)pl * Hp * Wp;
        int per = 2 * Wp + 2 * H;
        for (int i = threadIdx.x; i < per; i += 256) {
            int off;
            if (i < Wp) off = i;
            else if (i < 2 * Wp) off = (Hp - 1) * Wp + (i - Wp);
            else { int j = i - 2 * Wp; int r = j >> 1;
                   off = (r + 1) * Wp + ((j & 1) ? Wp - 1 : 0); }
            p[off] = 0.f;
        }
    }
}

__global__ __launch_bounds__(256)
void pad_x(const float* __restrict__ x, float* __restrict__ xp) {
    int idx = blockIdx.x * 256 + threadIdx.x;
    if (idx >= 6 * 50176) return;
    int c = idx / 50176, hw = idx - c * 50176;
    int h = hw / 224, w = hw - h * 224;
    xp[(c * 226 + h + 1) * 226 + (w + 1)] = x[idx];
}

__global__ __launch_bounds__(256)
void pool_k(const float* __restrict__ in, float* __restrict__ out,
            int planes, int Ho, int Wo, int ipitch, int iplane,
            int opitch, int oplane, int ooff) {
    int idx = blockIdx.x * 256 + threadIdx.x;
    if (idx >= planes * Ho * Wo) return;
    int p = idx / (Ho * Wo), r = idx - p * (Ho * Wo);
    int ho = r / Wo, wo = r - ho * Wo;
    const float* ib = in + (size_t)p * iplane + (size_t)(2 * ho + 1) * ipitch + (2 * wo + 1);
    float m = fmaxf(fmaxf(ib[0], ib[1]), fmaxf(ib[ipitch], ib[ipitch + 1]));
    out[(size_t)p * oplane + (size_t)ho * opitch + wo + ooff] = m;
}

__global__ __launch_bounds__(256)
void chan_minmax(const float* __restrict__ in, float* __restrict__ mn,
                 float* __restrict__ mx, int C, int H, int W) {
    int c = blockIdx.x;
    int Wp = W + 2, plane = (H + 2) * Wp;
    float lmn = INFINITY, lmx = -INFINITY;
    for (int n = 0; n < 2; ++n) {
        const float* p = in + (size_t)(n * C + c) * plane + Wp + 1;
        for (int i = threadIdx.x; i < H * W; i += 256) {
            int h = i / W, w = i - h * W;
            float v = p[h * Wp + w];
            lmn = fminf(lmn, v); lmx = fmaxf(lmx, v);
        }
    }
    __shared__ float smn[4], smx[4];
#pragma unroll
    for (int off = 32; off >= 1; off >>= 1) {
        lmn = fminf(lmn, __shfl_down(lmn, off, 64));
        lmx = fmaxf(lmx, __shfl_down(lmx, off, 64));
    }
    int wave = threadIdx.x >> 6;
    if ((threadIdx.x & 63) == 0) { smn[wave] = lmn; smx[wave] = lmx; }
    __syncthreads();
    if (threadIdx.x == 0) {
        float a = smn[0], b = smx[0];
        for (int i = 1; i < 4; ++i) { a = fminf(a, smn[i]); b = fmaxf(b, smx[i]); }
        mn[c] = a; mx[c] = b;
    }
}

__global__ __launch_bounds__(256)
void quant_apply(float* __restrict__ x, const float* __restrict__ mn,
                 const float* __restrict__ mx, int C, int H, int W) {
    int total = 2 * C * H * W;
    int idx = blockIdx.x * 256 + threadIdx.x;
    if (idx >= total) return;
    int w = idx % W;
    int t = idx / W;
    int h = t % H;
    t /= H;                       // t = n*C + c
    int c = t % C;
    int Wp = W + 2;
    size_t addr = ((size_t)t * (H + 2) + h + 1) * Wp + w + 1;
    float m = mn[c];
    float zd = mx[c] - m;
    float s = 255.f / zd;
    float inv = zd / 255.f;
    float v = x[addr];
    x[addr] = m + rintf((v - m) * s) * inv;
}

// ---------------------------------------------------------------------------
// FC (fp32, HBM-bound on weights): bias-init + split-K atomics + relu
// ---------------------------------------------------------------------------
__global__ __launch_bounds__(256)
void fc_init(const float* __restrict__ b, float* __restrict__ out, int dout) {
    int i = blockIdx.x * blockDim.x + threadIdx.x;
    if (i < 2 * dout) out[i] = b[i % dout];
}

__global__ __launch_bounds__(256)
void fc_splitk(const float* __restrict__ h, const float* __restrict__ w,
               float* __restrict__ out, int din, int dout, int chunk) {
    int o4 = blockIdx.x * blockDim.x + threadIdx.x;
    int o = o4 * 4;
    if (o >= dout) return;
    int d0 = blockIdx.y * chunk;
    int d1 = min(d0 + chunk, din);
    float4 a0 = {0.f, 0.f, 0.f, 0.f};
    float4 a1 = {0.f, 0.f, 0.f, 0.f};
    for (int d = d0; d < d1; ++d) {
        float4 wv = *(const float4*)(w + (size_t)d * dout + o);
        float h0 = h[d];
        float h1 = h[din + d];
        a0.x = fmaf(h0, wv.x, a0.x); a0.y = fmaf(h0, wv.y, a0.y);
        a0.z = fmaf(h0, wv.z, a0.z); a0.w = fmaf(h0, wv.w, a0.w);
        a1.x = fmaf(h1, wv.x, a1.x); a1.y = fmaf(h1, wv.y, a1.y);
        a1.z = fmaf(h1, wv.z, a1.z); a1.w = fmaf(h1, wv.w, a1.w);
    }
    atomicAdd(&out[o + 0], a0.x); atomicAdd(&out[o + 1], a0.y);
    atomicAdd(&out[o + 2], a0.z); atomicAdd(&out[o + 3], a0.w);
    atomicAdd(&out[dout + o + 0], a1.x); atomicAdd(&out[dout + o + 1], a1.y);
    atomicAdd(&out[dout + o + 2], a1.z); atomicAdd(&out[dout + o + 3], a1.w);
}

__global__ __launch_bounds__(256)
void relu_k(float* __restrict__ x, int n) {
    int i = blockIdx.x * blockDim.x + threadIdx.x;
    if (i < n) x[i] = fmaxf(x[i], 0.f);
}

// ---------------------------------------------------------------------------
// Host orchestration
// ---------------------------------------------------------------------------
static void launch_conv(int CIN, const float* in, const ushort* wbf,
                        const float* bias, float* out, int H, int W, int Cout,
                        hipStream_t s) {
    int tw = DIV_UP(W, 8), th = DIV_UP(H, 8);
    dim3 g(tw * th, Cout / 64, 2);
    switch (CIN) {
        case 3:   conv_mfma<3>  <<<g, 256, 0, s>>>(in, wbf, bias, out, H, W, tw); break;
        case 64:  conv_mfma<64> <<<g, 256, 0, s>>>(in, wbf, bias, out, H, W, tw); break;
        case 128: conv_mfma<128><<<g, 256, 0, s>>>(in, wbf, bias, out, H, W, tw); break;
        case 256: conv_mfma<256><<<g, 256, 0, s>>>(in, wbf, bias, out, H, W, tw); break;
        case 512: conv_mfma<512><<<g, 256, 0, s>>>(in, wbf, bias, out, H, W, tw); break;
    }
}

extern "C" void kernel_launch(void* const* d_in, const int* in_sizes, int n_in,
                              void* d_out, int out_size, void* d_ws, size_t ws_size,
                              hipStream_t stream) {
    const float* x = (const float*)d_in[0];
    const float* cw[13];
    const float* cb[13];
    for (int i = 0; i < 13; ++i) {
        cw[i] = (const float*)d_in[1 + 2 * i];
        cb[i] = (const float*)d_in[2 + 2 * i];
    }
    const float* fw1 = (const float*)d_in[27];
    const float* fb1 = (const float*)d_in[28];
    const float* fw2 = (const float*)d_in[29];
    const float* fb2 = (const float*)d_in[30];
    const float* fw3 = (const float*)d_in[31];
    const float* fb3 = (const float*)d_in[32];

    char* ws = (char*)d_ws;
    const size_t BUF = (size_t)2 * 64 * 226 * 226 * 4;   // 26,150,912 B
    float*  bufA = (float*)ws;
    float*  bufB = (float*)(ws + BUF);
    ushort* wscr = (ushort*)(ws + 2 * BUF);              // 4,718,592 B max
    float*  fc1  = (float*)(ws + 2 * BUF + 4718592);
    float*  fc2  = fc1 + 8192;
    float*  mn   = fc2 + 8192;
    float*  mx   = mn + 64;

    // layer configs: cin, cout, H(=W)
    const int LCI[13] = {3,64, 64,128, 128,256,256, 256,512,512, 512,512,512};
    const int LCO[13] = {64,64, 128,128, 256,256,256, 512,512,512, 512,512,512};
    const int LHW[13] = {224,224, 112,112, 56,56,56, 28,28,28, 14,14,14};

    auto wz = [&](int l, float* dsthalo) {
        int ktot = 9 * LCI[l];
        int kpad = (ktot + 31) & ~31;
        int wblocks = DIV_UP(LCO[l] * kpad, 256);
        int planes = 2 * LCO[l];
        wconv_zh<<<wblocks + planes, 256, 0, stream>>>(
            cw[l], wscr, LCI[l], LCO[l], wblocks, dsthalo, planes, LHW[l], LHW[l]);
    };
    auto conv = [&](int l, const float* in, float* out) {
        launch_conv(LCI[l], in, wscr, cb[l], out, LHW[l], LHW[l], LCO[l], stream);
    };
    auto zh = [&](float* buf, int planes, int HW) {
        wconv_zh<<<planes, 256, 0, stream>>>(nullptr, nullptr, 1, 0, 0,
                                             buf, planes, HW, HW);
    };
    auto pool = [&](const float* in, float* out, int planes, int Hin, bool flat) {
        int Ho = Hin / 2;
        int ip = Hin + 2, op = flat ? Ho : Ho + 2;
        pool_k<<<DIV_UP(planes * Ho * Ho, 256), 256, 0, stream>>>(
            in, out, planes, Ho, Ho, ip, ip * ip, op, op * op,
            flat ? 0 : op + 1);
    };

    // input pad (xpad lives at start of bufB; L0 reads it, writes bufA)
    hipMemsetAsync(bufB, 0, (size_t)6 * 226 * 226 * 4, stream);
    pad_x<<<DIV_UP(6 * 50176, 256), 256, 0, stream>>>(x, bufB);

    wz(0, bufA);  conv(0, bufB, bufA);
    wz(1, bufB);  conv(1, bufA, bufB);
    zh(bufA, 128, 112);  pool(bufB, bufA, 128, 224, false);
    chan_minmax<<<64, 256, 0, stream>>>(bufA, mn, mx, 64, 112, 112);
    quant_apply<<<DIV_UP(2 * 64 * 112 * 112, 256), 256, 0, stream>>>(bufA, mn, mx, 64, 112, 112);
    wz(2, bufB);  conv(2, bufA, bufB);
    wz(3, bufA);  conv(3, bufB, bufA);
    zh(bufB, 256, 56);   pool(bufA, bufB, 256, 112, false);
    wz(4, bufA);  conv(4, bufB, bufA);
    wz(5, bufB);  conv(5, bufA, bufB);
    wz(6, bufA);  conv(6, bufB, bufA);
    zh(bufB, 512, 28);   pool(bufA, bufB, 512, 56, false);
    wz(7, bufA);  conv(7, bufB, bufA);
    wz(8, bufB);  conv(8, bufA, bufB);
    wz(9, bufA);  conv(9, bufB, bufA);
    zh(bufB, 1024, 14);  pool(bufA, bufB, 1024, 28, false);
    wz(10, bufA); conv(10, bufB, bufA);
    wz(11, bufB); conv(11, bufA, bufB);
    wz(12, bufA); conv(12, bufB, bufA);
    pool(bufA, bufB, 1024, 14, true);    // flat [2,25088] fp32 at bufB

    auto fc = [&](const float* h, const float* w, const float* b, float* out,
                  int din, int dout, int S, bool relu) {
        fc_init<<<DIV_UP(2 * dout, 256), 256, 0, stream>>>(b, out, dout);
        int chunk = DIV_UP(din, S);
        dim3 g(DIV_UP(dout / 4, 256), S);
        fc_splitk<<<g, 256, 0, stream>>>(h, w, out, din, dout, chunk);
        if (relu) relu_k<<<DIV_UP(2 * dout, 256), 256, 0, stream>>>(out, 2 * dout);
    };
    fc(bufB, fw1, fb1, fc1,           25088, 4096, 64, true);
    fc(fc1,  fw2, fb2, fc2,           4096,  4096, 32, true);
    fc(fc2,  fw3, fb3, (float*)d_out, 4096,  196,  64, false);
}